// Round 1
// baseline (152.090 us; speedup 1.0000x reference)
//
#include <hip/hip_runtime.h>

// WaveletLayer: per-row db2 DWT -> elementwise gain -> inverse DWT -> ReLU.
// B=4096 rows, N=4096 cols, L=(N+3)/2=2049 coefficients per band.
// Memory-bound: 64MB x + 33.6MB kernel read, 64MB out write (~161MB total).

#define BB 4096
#define NN 4096
#define LL 2049  // (NN+3)/2

__device__ __forceinline__ float xe_load(const float* s_x, int i /* xe index, 0..NN+5 */) {
    // xe = symmetric pad of x by 3 on each side: xe[i] = x[map(i-3)]
    int idx = i - 3;
    idx = (idx < 0) ? (-idx - 1) : idx;
    idx = (idx >= NN) ? (2 * NN - 1 - idx) : idx;
    return s_x[idx];
}

__global__ __launch_bounds__(256) void wavelet_fused(const float* __restrict__ x,
                                                     const float* __restrict__ ker,
                                                     float* __restrict__ out) {
    __shared__ float s_x[NN];
    __shared__ float s_a[LL + 1];
    __shared__ float s_d[LL + 1];

    const int row = blockIdx.x;
    const int tid = threadIdx.x;

    // db2 decomposition taps (pywt exact values)
    const float lo0 = -0.12940952255126037f, lo1 = 0.22414386804185735f,
                lo2 =  0.8365163037378079f,  lo3 = 0.48296291314453416f;
    const float hi0 = -0.48296291314453416f, hi1 = 0.8365163037378079f,
                hi2 = -0.22414386804185735f, hi3 = -0.12940952255126037f;

    // ---- phase 1: stage x row into LDS (coalesced float4) ----
    const float4* x4 = (const float4*)(x + (size_t)row * NN);
    float4* s_x4 = (float4*)s_x;
    #pragma unroll
    for (int i = tid; i < NN / 4; i += 256) s_x4[i] = x4[i];
    __syncthreads();

    // ---- phase 2: a[j] = cA[j]*g, d[j] = cD[j]*g ----
    // cA[j] = lo3*xe[2j+1] + lo2*xe[2j+2] + lo1*xe[2j+3] + lo0*xe[2j+4]
    const float* krow = ker + (size_t)row * LL;
    for (int j = tid; j < LL; j += 256) {
        const int m = 2 * j + 1;
        const float e0 = xe_load(s_x, m);
        const float e1 = xe_load(s_x, m + 1);
        const float e2 = xe_load(s_x, m + 2);
        const float e3 = xe_load(s_x, m + 3);
        const float cA = lo3 * e0 + lo2 * e1 + lo1 * e2 + lo0 * e3;
        const float cD = hi3 * e0 + hi2 * e1 + hi1 * e2 + hi0 * e3;
        const float g = krow[j];
        s_a[j] = cA * g;
        s_d[j] = cD * g;
    }
    __syncthreads();

    // ---- phase 3: inverse DWT + ReLU, one (even,odd) output pair per iter ----
    // y[2m]   = lo1*a[m] + lo3*a[m+1] + hi1*d[m] + hi3*d[m+1]
    // y[2m+1] = lo0*a[m] + lo2*a[m+1] + hi0*d[m] + hi2*d[m+1]
    float2* out2 = (float2*)(out + (size_t)row * NN);
    for (int m = tid; m < NN / 2; m += 256) {
        const float a0 = s_a[m], a1 = s_a[m + 1];
        const float d0 = s_d[m], d1 = s_d[m + 1];
        float y0 = lo1 * a0 + lo3 * a1 + hi1 * d0 + hi3 * d1;
        float y1 = lo0 * a0 + lo2 * a1 + hi0 * d0 + hi2 * d1;
        y0 = fmaxf(y0, 0.0f);
        y1 = fmaxf(y1, 0.0f);
        out2[m] = make_float2(y0, y1);
    }
}

extern "C" void kernel_launch(void* const* d_in, const int* in_sizes, int n_in,
                              void* d_out, int out_size, void* d_ws, size_t ws_size,
                              hipStream_t stream) {
    const float* x   = (const float*)d_in[0];
    const float* ker = (const float*)d_in[1];
    float* out = (float*)d_out;
    wavelet_fused<<<dim3(BB), dim3(256), 0, stream>>>(x, ker, out);
}

// Round 2
// 136.779 us; speedup vs baseline: 1.1119x; 1.1119x over previous
//
#include <hip/hip_runtime.h>

// WaveletLayer: db2 DWT -> gain -> IDWT -> ReLU, fused into a single 6-tap
// stencil. y[2m],y[2m+1] depend only on x[2m-2..2m+3] (symmetric-padded) and
// g[m],g[m+1]. No LDS, no barriers: 3 overlapping aligned float4 x-loads per
// thread (L1 dedupes), float4 stores. B=4096 rows, N=4096, L=2049.

#define NN 4096
#define LL 2049
#define PAIRS4 1024  // threads-tasks per row: each handles 4 outputs

__global__ __launch_bounds__(256) void wavelet_fused(const float* __restrict__ x,
                                                     const float* __restrict__ ker,
                                                     float* __restrict__ out) {
    const int row = blockIdx.y;
    const int t   = blockIdx.x * 256 + threadIdx.x;   // 0..1023: output quad index

    // db2 decomposition taps
    const float lo0 = -0.12940952255126037f, lo1 = 0.22414386804185735f,
                lo2 =  0.8365163037378079f,  lo3 = 0.48296291314453416f;
    const float hi0 = -0.48296291314453416f, hi1 = 0.8365163037378079f,
                hi2 = -0.22414386804185735f, hi3 = -0.12940952255126037f;

    const float4* x4 = (const float4*)(x + (size_t)row * NN);

    // x window X(4t-2 .. 4t+5); X(i) = x[sym_map(i)]
    const int tp = (t == 0) ? 0 : (t - 1);
    const int tn = (t == PAIRS4 - 1) ? t : (t + 1);
    const float4 vp = x4[tp];
    const float4 vc = x4[t];
    const float4 vn = x4[tn];

    // interior: e0..e7 = prev.z, prev.w, cur.xyzw, next.x, next.y
    const bool first = (t == 0);
    const bool last  = (t == PAIRS4 - 1);
    const float e0 = first ? vc.y : vp.z;   // X(-2) = x[1]
    const float e1 = first ? vc.x : vp.w;   // X(-1) = x[0]
    const float e2 = vc.x;
    const float e3 = vc.y;
    const float e4 = vc.z;
    const float e5 = vc.w;
    const float e6 = last ? vc.w : vn.x;    // X(4096) = x[4095]
    const float e7 = last ? vc.z : vn.y;    // X(4097) = x[4094]

    // gains g[2t], g[2t+1], g[2t+2]  (2t+2 <= 2048 = LL-1, always valid)
    const float* krow = ker + (size_t)row * LL;
    const float g0 = krow[2 * t];
    const float g1 = krow[2 * t + 1];
    const float g2 = krow[2 * t + 2];

    // analysis: cA[j] = lo3*X(2j-2)+lo2*X(2j-1)+lo1*X(2j)+lo0*X(2j+1)
    const float cA0 = lo3 * e0 + lo2 * e1 + lo1 * e2 + lo0 * e3;
    const float cD0 = hi3 * e0 + hi2 * e1 + hi1 * e2 + hi0 * e3;
    const float cA1 = lo3 * e2 + lo2 * e3 + lo1 * e4 + lo0 * e5;
    const float cD1 = hi3 * e2 + hi2 * e3 + hi1 * e4 + hi0 * e5;
    const float cA2 = lo3 * e4 + lo2 * e5 + lo1 * e6 + lo0 * e7;
    const float cD2 = hi3 * e4 + hi2 * e5 + hi1 * e6 + hi0 * e7;

    const float A0 = g0 * cA0, D0 = g0 * cD0;
    const float A1 = g1 * cA1, D1 = g1 * cD1;
    const float A2 = g2 * cA2, D2 = g2 * cD2;

    // synthesis: y[2m] = lo1*A[m]+lo3*A[m+1]+hi1*D[m]+hi3*D[m+1]
    //            y[2m+1] = lo0*A[m]+lo2*A[m+1]+hi0*D[m]+hi2*D[m+1]
    float y0 = lo1 * A0 + lo3 * A1 + hi1 * D0 + hi3 * D1;
    float y1 = lo0 * A0 + lo2 * A1 + hi0 * D0 + hi2 * D1;
    float y2 = lo1 * A1 + lo3 * A2 + hi1 * D1 + hi3 * D2;
    float y3 = lo0 * A1 + lo2 * A2 + hi0 * D1 + hi2 * D2;

    y0 = fmaxf(y0, 0.0f);
    y1 = fmaxf(y1, 0.0f);
    y2 = fmaxf(y2, 0.0f);
    y3 = fmaxf(y3, 0.0f);

    float4* out4 = (float4*)(out + (size_t)row * NN);
    out4[t] = make_float4(y0, y1, y2, y3);
}

extern "C" void kernel_launch(void* const* d_in, const int* in_sizes, int n_in,
                              void* d_out, int out_size, void* d_ws, size_t ws_size,
                              hipStream_t stream) {
    const float* x   = (const float*)d_in[0];
    const float* ker = (const float*)d_in[1];
    float* out = (float*)d_out;
    wavelet_fused<<<dim3(PAIRS4 / 256, 4096), dim3(256), 0, stream>>>(x, ker, out);
}